// Round 2
// baseline (575.250 us; speedup 1.0000x reference)
//
#include <hip/hip_runtime.h>
#include <stdint.h>

#define LBL 50
#define NL 52
#define NEGV (-100.0f)
#define L2E 1.4426950408889634f
#define BB 128
#define SS 512
#define DD 1024

typedef __attribute__((ext_vector_type(8))) short short8;
typedef __attribute__((ext_vector_type(4))) float float4v;

static __device__ __forceinline__ unsigned int f2bf(float f) {
    union { float f; unsigned int u; } v; v.f = f;
    unsigned int r = v.u + 0x7fffu + ((v.u >> 16) & 1u);
    return r >> 16;
}

static __device__ __forceinline__ float readlane0(float x) {
    return __int_as_float(__builtin_amdgcn_readfirstlane(__float_as_int(x)));
}

// ---------------------------------------------------------------------------
// Kernel 1: logits[r, l] = sum_d A[r,d]*W[l,d] + bias[l]   (r = b*S+s)
// bf16 MFMA, memory-bound on A (256 MB). Block: 64 rows x 64 cols (50 valid).
// (unchanged from R1 — known correct; counters next round attribute its cost)
// ---------------------------------------------------------------------------
__global__ __launch_bounds__(256) void gemm_logits(
    const float* __restrict__ A,    // [65536,1024]
    const float* __restrict__ W,    // [50,1024]
    const float* __restrict__ bias, // [50]
    float* __restrict__ out)        // [65536,50]
{
    __shared__ __align__(16) unsigned short As[64 * 72];
    __shared__ __align__(16) unsigned short Ws[64 * 72];

    const int tid  = threadIdx.x;
    const int m0   = blockIdx.x * 64;
    const int lane = tid & 63;
    const int wv   = tid >> 6;
    const int mrow = lane & 15;
    const int quad = lane >> 4;

    float4v acc[4];
#pragma unroll
    for (int i = 0; i < 4; ++i) acc[i] = (float4v){0.f, 0.f, 0.f, 0.f};

    for (int kc = 0; kc < DD; kc += 64) {
        __syncthreads();
#pragma unroll
        for (int p = 0; p < 4; ++p) {
            int idx = tid + p * 256;
            int r = idx >> 4, kq = idx & 15;
            const float4 v = *(const float4*)(A + (size_t)(m0 + r) * DD + kc + kq * 4);
            unsigned int lo = f2bf(v.x) | (f2bf(v.y) << 16);
            unsigned int hi = f2bf(v.z) | (f2bf(v.w) << 16);
            uint2 pk; pk.x = lo; pk.y = hi;
            *(uint2*)&As[r * 72 + kq * 4] = pk;
        }
#pragma unroll
        for (int p = 0; p < 4; ++p) {
            int idx = tid + p * 256;
            int r = idx >> 4, kq = idx & 15;
            float4 v = {0.f, 0.f, 0.f, 0.f};
            if (r < LBL) v = *(const float4*)(W + (size_t)r * DD + kc + kq * 4);
            unsigned int lo = f2bf(v.x) | (f2bf(v.y) << 16);
            unsigned int hi = f2bf(v.z) | (f2bf(v.w) << 16);
            uint2 pk; pk.x = lo; pk.y = hi;
            *(uint2*)&Ws[r * 72 + kq * 4] = pk;
        }
        __syncthreads();
#pragma unroll
        for (int ks = 0; ks < 64; ks += 32) {
            short8 a = *(const short8*)&As[(wv * 16 + mrow) * 72 + ks + quad * 8];
#pragma unroll
            for (int nt = 0; nt < 4; ++nt) {
                short8 b = *(const short8*)&Ws[(nt * 16 + mrow) * 72 + ks + quad * 8];
                acc[nt] = __builtin_amdgcn_mfma_f32_16x16x32_bf16(a, b, acc[nt], 0, 0, 0);
            }
        }
    }
#pragma unroll
    for (int nt = 0; nt < 4; ++nt) {
        int col = nt * 16 + mrow;
        if (col < LBL) {
            float bv = bias[col];
#pragma unroll
            for (int r = 0; r < 4; ++r) {
                int row = m0 + wv * 16 + quad * 4 + r;
                out[(size_t)row * LBL + col] = acc[nt][r] + bv;
            }
        }
    }
}

// ---------------------------------------------------------------------------
// Kernel 2: per-batch CRF forward recursion (wave 0) + gold score (wave 1).
// Latency-tuned: depth-4 global prefetch ring (covers ~900cyc HBM latency),
// 2-step-stale reference M (readfirstlane off the carried path), no lane
// masking in the loop (lanes 52..63 hold finite garbage, never read), 8
// accumulators (7-deep FMA tail).
// ---------------------------------------------------------------------------
__global__ __launch_bounds__(128) void crf_seq(
    const float* __restrict__ logits, // [B*S, 50], base-e
    const float* __restrict__ T,      // [52,52]
    const int*   __restrict__ lens,   // [128]
    const int*   __restrict__ labels, // [128,512]
    float* __restrict__ out)          // [1], pre-zeroed
{
    const int b    = blockIdx.x;
    const int tid  = threadIdx.x;
    const int lane = tid & 63;
    const int len  = lens[b];
    const size_t bo = (size_t)b * SS;

    __shared__ __align__(16) float E_sh[64];
    __shared__ float red[2];

    if (tid < 64) {
        // ---------------- wave 0: recursion ----------------
        const int i = (lane < NL) ? lane : (NL - 1);
        float ET[NL]; // e^{T[i][j]} in registers
#pragma unroll
        for (int jq = 0; jq < 13; ++jq) {
            float4 tv = *(const float4*)(T + i * NL + jq * 4);
            ET[jq * 4 + 0] = __builtin_amdgcn_exp2f(tv.x * L2E);
            ET[jq * 4 + 1] = __builtin_amdgcn_exp2f(tv.y * L2E);
            ET[jq * 4 + 2] = __builtin_amdgcn_exp2f(tv.z * L2E);
            ET[jq * 4 + 3] = __builtin_amdgcn_exp2f(tv.w * L2E);
        }
        // t = 0 analytically: alpha1[i] = logit0[i] + T[i][START]
        float lg0 = (lane < LBL) ? logits[bo * LBL + lane] : NEGV;
        float tS  = T[i * NL + LBL]; // col START=50
        float a2  = (lg0 + tS) * L2E;              // finite in all lanes
        float Muse = readlane0(a2);                // M used this step
        float Mpend = Muse;                        // M pending (1 behind)

        // depth-4 prefetch ring of RAW logit values (clamped, in-bounds)
        int t1 = (1 < len) ? 1 : len - 1;
        int t2 = (2 < len) ? 2 : len - 1;
        int t3 = (3 < len) ? 3 : len - 1;
        int t4 = (4 < len) ? 4 : len - 1;
        float p0 = (lane < LBL) ? logits[(bo + t1) * LBL + lane] : NEGV;
        float p1 = (lane < LBL) ? logits[(bo + t2) * LBL + lane] : NEGV;
        float p2 = (lane < LBL) ? logits[(bo + t3) * LBL + lane] : NEGV;
        float p3 = (lane < LBL) ? logits[(bo + t4) * LBL + lane] : NEGV;

        for (int t = 1; t < len; ++t) {
            float lgraw = p0;
            p0 = p1; p1 = p2; p2 = p3;
            int tn = (t + 5 < len) ? (t + 5) : (len - 1);
            p3 = (lane < LBL) ? logits[(bo + tn) * LBL + lane] : NEGV;

            float E = __builtin_amdgcn_exp2f(a2 - Muse);
            E_sh[lane] = E;
            __builtin_amdgcn_wave_barrier();

            float s0 = 0.f, s1 = 0.f, s2 = 0.f, s3 = 0.f;
            float s4 = 0.f, s5 = 0.f, s6 = 0.f, s7 = 0.f;
#pragma unroll
            for (int jq = 0; jq < 13; ++jq) {
                float4v e4 = *(const float4v*)&E_sh[jq * 4];
                if (jq & 1) {
                    s4 += e4.x * ET[jq * 4 + 0];
                    s5 += e4.y * ET[jq * 4 + 1];
                    s6 += e4.z * ET[jq * 4 + 2];
                    s7 += e4.w * ET[jq * 4 + 3];
                } else {
                    s0 += e4.x * ET[jq * 4 + 0];
                    s1 += e4.y * ET[jq * 4 + 1];
                    s2 += e4.z * ET[jq * 4 + 2];
                    s3 += e4.w * ET[jq * 4 + 3];
                }
            }
            __builtin_amdgcn_wave_barrier();
            float sum = ((s0 + s4) + (s1 + s5)) + ((s2 + s6) + (s3 + s7));
            // a2' = lgraw*log2(e) + Muse + log2(sum)   (exact for any Muse)
            float base = Muse + __builtin_amdgcn_logf(sum);
            a2 = __builtin_fmaf(lgraw, L2E, base);
            // rotate M: use value that is 2 steps stale -> readlane off path
            Muse = Mpend;
            Mpend = readlane0(a2);
        }

        // norm = lse_j(alpha_j + T[END][j]); Mpend = readlane0(final a2)
        float v = 0.f;
        if (lane < NL) {
            float tE = T[(NL - 1) * NL + lane]; // row END=51
            v = __builtin_amdgcn_exp2f(a2 + tE * L2E - Mpend);
        }
#pragma unroll
        for (int m = 32; m; m >>= 1) v += __shfl_xor(v, m, 64);
        float norm_e = (Mpend + __builtin_amdgcn_logf(v)) * (1.0f / L2E);
        if (lane == 0) red[0] = norm_e;
    } else {
        // ---------------- wave 1: gold score ----------------
        float un = 0.f, bi = 0.f;
        for (int t = lane; t < len; t += 64) {
            int lab = labels[bo + t];
            un += logits[(bo + t) * LBL + lab];
            int prev = (t == 0) ? LBL : labels[bo + t - 1]; // START=50
            bi += T[lab * NL + prev];
        }
        float g = un + bi;
#pragma unroll
        for (int m = 32; m; m >>= 1) g += __shfl_xor(g, m, 64);
        if (lane == 0) {
            int lastLab = labels[bo + len - 1];
            g += T[(NL - 1) * NL + lastLab]; // T[END, l_{len-1}]
            red[1] = g;
        }
    }
    __syncthreads();
    if (tid == 0) atomicAdd(out, red[0] - red[1]); // loss = sum(norm - gold)
}

// ---------------------------------------------------------------------------
extern "C" void kernel_launch(void* const* d_in, const int* in_sizes, int n_in,
                              void* d_out, int out_size, void* d_ws, size_t ws_size,
                              hipStream_t stream) {
    const float* A      = (const float*)d_in[0]; // inputs [128,512,1024]
    const float* W      = (const float*)d_in[1]; // [50,1024]
    const float* bias   = (const float*)d_in[2]; // [50]
    const float* T      = (const float*)d_in[3]; // [52,52]
    const int*   lens   = (const int*)d_in[4];   // [128]
    const int*   labels = (const int*)d_in[5];   // [128,512]
    float* out = (float*)d_out;
    float* logits = (float*)d_ws;                // 65536*50*4 = 13.1 MB

    hipMemsetAsync(d_out, 0, sizeof(float), stream);
    gemm_logits<<<dim3((BB * SS) / 64), dim3(256), 0, stream>>>(A, W, bias, logits);
    crf_seq<<<dim3(BB), dim3(128), 0, stream>>>(logits, T, lens, labels, out);
}

// Round 3
// 570.594 us; speedup vs baseline: 1.0082x; 1.0082x over previous
//
#include <hip/hip_runtime.h>
#include <stdint.h>

#define LBL 50
#define NL 52
#define NEGV (-100.0f)
#define L2E 1.4426950408889634f
#define BB 128
#define SS 512
#define DD 1024

typedef __attribute__((ext_vector_type(8))) short short8;
typedef __attribute__((ext_vector_type(4))) float float4v;
typedef __attribute__((ext_vector_type(4), aligned(4))) float float4u; // 4B-aligned vec load

union S8U { unsigned int u[4]; short8 s; };

static __device__ __forceinline__ unsigned int f2bf(float f) {
    union { float f; unsigned int u; } v; v.f = f;
    unsigned int r = v.u + 0x7fffu + ((v.u >> 16) & 1u);
    return r >> 16;
}

// ---------------------------------------------------------------------------
// Kernel 1: PE[r, l] = exp(sum_d A[r,d]*W[l,d] + bias[l])   (r = b*S+s)
// bf16 MFMA, memory-bound on A (256 MB). Epilogue applies exp2(x*log2e) so the
// recursion kernel can stay entirely in the exp domain.
// ---------------------------------------------------------------------------
__global__ __launch_bounds__(256) void gemm_logits(
    const float* __restrict__ A,    // [65536,1024]
    const float* __restrict__ W,    // [50,1024]
    const float* __restrict__ bias, // [50]
    float* __restrict__ out)        // [65536,50] = exp(logits)
{
    __shared__ __align__(16) unsigned short As[64 * 72];
    __shared__ __align__(16) unsigned short Ws[64 * 72];

    const int tid  = threadIdx.x;
    const int m0   = blockIdx.x * 64;
    const int lane = tid & 63;
    const int wv   = tid >> 6;
    const int mrow = lane & 15;
    const int quad = lane >> 4;

    float4v acc[4];
#pragma unroll
    for (int i = 0; i < 4; ++i) acc[i] = (float4v){0.f, 0.f, 0.f, 0.f};

    for (int kc = 0; kc < DD; kc += 64) {
        __syncthreads();
#pragma unroll
        for (int p = 0; p < 4; ++p) {
            int idx = tid + p * 256;
            int r = idx >> 4, kq = idx & 15;
            const float4 v = *(const float4*)(A + (size_t)(m0 + r) * DD + kc + kq * 4);
            unsigned int lo = f2bf(v.x) | (f2bf(v.y) << 16);
            unsigned int hi = f2bf(v.z) | (f2bf(v.w) << 16);
            uint2 pk; pk.x = lo; pk.y = hi;
            *(uint2*)&As[r * 72 + kq * 4] = pk;
        }
#pragma unroll
        for (int p = 0; p < 4; ++p) {
            int idx = tid + p * 256;
            int r = idx >> 4, kq = idx & 15;
            float4 v = {0.f, 0.f, 0.f, 0.f};
            if (r < LBL) v = *(const float4*)(W + (size_t)r * DD + kc + kq * 4);
            unsigned int lo = f2bf(v.x) | (f2bf(v.y) << 16);
            unsigned int hi = f2bf(v.z) | (f2bf(v.w) << 16);
            uint2 pk; pk.x = lo; pk.y = hi;
            *(uint2*)&Ws[r * 72 + kq * 4] = pk;
        }
        __syncthreads();
#pragma unroll
        for (int ks = 0; ks < 64; ks += 32) {
            short8 a = *(const short8*)&As[(wv * 16 + mrow) * 72 + ks + quad * 8];
#pragma unroll
            for (int nt = 0; nt < 4; ++nt) {
                short8 b = *(const short8*)&Ws[(nt * 16 + mrow) * 72 + ks + quad * 8];
                acc[nt] = __builtin_amdgcn_mfma_f32_16x16x32_bf16(a, b, acc[nt], 0, 0, 0);
            }
        }
    }
#pragma unroll
    for (int nt = 0; nt < 4; ++nt) {
        int col = nt * 16 + mrow;
        if (col < LBL) {
            float bv = bias[col];
#pragma unroll
            for (int r = 0; r < 4; ++r) {
                int row = m0 + wv * 16 + quad * 4 + r;
                float lg = acc[nt][r] + bv;
                out[(size_t)row * LBL + col] = __builtin_amdgcn_exp2f(lg * L2E);
            }
        }
    }
}

// ---------------------------------------------------------------------------
// Kernel 2: MFMA-batched CRF forward. 8 blocks x (wave0: 16 chains recursion,
// wave1: gold scores for same 16 chains).
//
// State E[j][b] = e^{alpha_j(b)} * 2^{lsum_b}, held in MFMA C-layout:
//   lane (b = lane&15, q = lane>>4) holds E[i][b], i = tile*16 + q*4 + r.
// Step: D = ET_mfma(E)  (8x mfma 16x16x32 bf16, A = e^T constant),
//       capture D[51][b] at t == len_b  (row END dot product = finish),
//       E' = D * PE[t] * (stale per-batch 2^-e rescale).
// C->B layout transform: 8 v_perm bf16 packs + 16 ds_bpermute + 8 selects.
// ---------------------------------------------------------------------------
__global__ __launch_bounds__(128) void crf_fwd(
    const float* __restrict__ PE,     // [65536,50] = exp(logits)
    const float* __restrict__ T,      // [52,52]
    const int*   __restrict__ lens,   // [128]
    const int*   __restrict__ labels, // [128,512]
    float* __restrict__ out)          // [1], pre-zeroed
{
    const int g    = blockIdx.x;   // 8 groups of 16 batches
    const int tid  = threadIdx.x;
    const int lane = tid & 63;
    const int wv   = tid >> 6;
    const int b    = lane & 15;
    const int q    = lane >> 4;

    __shared__ float gold_sh[16];
    float norm_e = 0.f;

    if (wv == 0) {
        const int bb = g * 16 + b;
        const int lenl = lens[bb];

        // ---- constant A-frags: ET[i][k], A[m=lane&15][k=q*8+reg] ----
        short8 afr[4][2];
#pragma unroll
        for (int it = 0; it < 4; ++it) {
            int i = it * 16 + b;
#pragma unroll
            for (int jt = 0; jt < 2; ++jt) {
                S8U pk;
#pragma unroll
                for (int h = 0; h < 4; ++h) {
                    int k0 = jt * 32 + q * 8 + 2 * h;
                    float v0 = (i < NL && k0     < NL) ? __builtin_amdgcn_exp2f(T[i * NL + k0]     * L2E) : 0.f;
                    float v1 = (i < NL && k0 + 1 < NL) ? __builtin_amdgcn_exp2f(T[i * NL + k0 + 1] * L2E) : 0.f;
                    pk.u[h] = f2bf(v0) | (f2bf(v1) << 16);
                }
                afr[it][jt] = pk.s;
            }
        }

        // bpermute addresses (loop-invariant)
        const int addrLo = (b + 16 * ((q & 1) * 2 + 0)) * 4;
        const int addrHi = (b + 16 * ((q & 1) * 2 + 1)) * 4;
        const int addrB  = b * 4;
        const bool qhi = (q >= 2);

#define LOADPE(dst, row) do {                                            \
        const float* _bp = PE + (size_t)(row) * LBL;                     \
        float4u _t0 = *(const float4u*)(_bp + q * 4);                    \
        float4u _t1 = *(const float4u*)(_bp + 16 + q * 4);               \
        float4u _t2 = *(const float4u*)(_bp + 32 + q * 4);               \
        dst[0]=_t0.x; dst[1]=_t0.y; dst[2]=_t0.z;  dst[3]=_t0.w;         \
        dst[4]=_t1.x; dst[5]=_t1.y; dst[6]=_t1.z;  dst[7]=_t1.w;         \
        dst[8]=_t2.x; dst[9]=_t2.y; dst[10]=_t2.z; dst[11]=_t2.w;        \
        float _x = 0.f, _y = 0.f;                                        \
        if (q == 0) { _x = _bp[48]; _y = _bp[49]; }                      \
        dst[12]=_x; dst[13]=_y; dst[14]=0.f; dst[15]=0.f;                \
    } while (0)

        // ---- init E_1[i][b] = PE[row0][i] * e^{T[i][START]} ----
        float E[16];
        {
            float p0[16];
            LOADPE(p0, (size_t)bb * SS + 0);
#pragma unroll
            for (int k = 0; k < 16; ++k) {
                int i = (k >> 2) * 16 + q * 4 + (k & 3);
                float ets = (i < NL) ? __builtin_amdgcn_exp2f(T[i * NL + LBL] * L2E) : 0.f;
                E[k] = p0[k] * ets;
            }
        }

        float pC[16], pN[16];
        LOADPE(pC, (size_t)bb * SS + 1);

        float ncap = 1.0f, lcap = 0.f, lsum = 0.f;
        int pendE = 127;

#pragma unroll 4
        for (int t = 1; t <= SS; ++t) {
            // prefetch PE row for next iteration (row index clamped to S-1)
            int tn = (t + 1 < SS) ? (t + 1) : (SS - 1);
            LOADPE(pN, (size_t)bb * SS + tn);

            // ---- pack E (C-layout) into 8 bf16-pair uints ----
            unsigned int pr[4][2];
#pragma unroll
            for (int tile = 0; tile < 4; ++tile) {
#pragma unroll
                for (int h = 0; h < 2; ++h) {
                    unsigned int lo = __float_as_uint(E[tile * 4 + 2 * h]);
                    unsigned int hi = __float_as_uint(E[tile * 4 + 2 * h + 1]);
                    pr[tile][h] = __builtin_amdgcn_perm(hi, lo, 0x07060302u);
                }
            }

            // ---- C->B transform: 16 bpermute + 8 select ----
            S8U bfr[2];
#pragma unroll
            for (int jt = 0; jt < 2; ++jt) {
#pragma unroll
                for (int u = 0; u < 4; ++u) {
                    int adr = (u < 2) ? addrLo : addrHi;
                    int vLo = __builtin_amdgcn_ds_bpermute(adr, (int)pr[jt * 2 + 0][u & 1]);
                    int vHi = __builtin_amdgcn_ds_bpermute(adr, (int)pr[jt * 2 + 1][u & 1]);
                    bfr[jt].u[u] = (unsigned int)(qhi ? vHi : vLo);
                }
            }

            // ---- 8 MFMAs: D[i][b] = sum_j ET[i][j] E[j][b] ----
            const float4v zz = (float4v){0.f, 0.f, 0.f, 0.f};
            float4v acc[4];
#pragma unroll
            for (int it = 0; it < 4; ++it) {
                float4v a0 = __builtin_amdgcn_mfma_f32_16x16x32_bf16(afr[it][0], bfr[0].s, zz, 0, 0, 0);
                acc[it]    = __builtin_amdgcn_mfma_f32_16x16x32_bf16(afr[it][1], bfr[1].s, a0, 0, 0, 0);
            }

            // ---- capture norm numerator at t == len_b (D[51][b] in q0:acc[3].w) ----
            bool cap = (t == lenl);
            ncap = cap ? acc[3][3] : ncap;
            lcap = cap ? lsum : lcap;

            // ---- anchored rescale: compute at even t, apply at odd t (stale) ----
            if ((t & 1) == 0) {
                int myeb = (int)(__float_as_uint(acc[0][0]) >> 23); // anchor D[0][b], q0 lanes
                pendE = __builtin_amdgcn_ds_bpermute(addrB, myeb);
            }
            float s = 1.0f;
            if ((t & 1) == 1) {
                s = __uint_as_float((unsigned int)(254 - pendE) << 23); // 2^(127-eb)
                lsum += (float)(127 - pendE);
            }

            // ---- E update: E' = D * PE[t] (* s) ----
#pragma unroll
            for (int k = 0; k < 16; ++k) {
                float d = acc[k >> 2][k & 3];
                E[k] = d * pC[k] * s;
            }
#pragma unroll
            for (int k = 0; k < 16; ++k) pC[k] = pN[k];
        }

        // norm_b = (log2(ncap) - lsum_at_capture) / log2(e)   (lanes 0..15 valid)
        norm_e = (__builtin_amdgcn_logf(ncap) - lcap) * (1.0f / L2E);
    } else {
        // ---------------- wave 1: gold scores, 4 lanes per batch ----------------
        const int lb = lane >> 2;
        const int ph = lane & 3;
        const int bb = g * 16 + lb;
        const int len = lens[bb];
        const size_t base = (size_t)bb * SS;
        float un2 = 0.f, bi = 0.f;
        for (int t = ph; t < len; t += 4) {
            int lab = labels[base + t];
            un2 += __builtin_amdgcn_logf(PE[(base + t) * LBL + lab]); // log2
            int prev = (t == 0) ? LBL : labels[base + t - 1];
            bi += T[lab * NL + prev];
        }
        float gsum = un2 * (1.0f / L2E) + bi;
        gsum += __shfl_xor(gsum, 1, 64);
        gsum += __shfl_xor(gsum, 2, 64);
        if (ph == 0) {
            gsum += T[(NL - 1) * NL + labels[base + len - 1]];
            gold_sh[lb] = gsum;
        }
    }

    __syncthreads();
    if (wv == 0 && q == 0) { // lanes 0..15
        float v = norm_e - gold_sh[b];
        v += __shfl_xor(v, 1, 64);
        v += __shfl_xor(v, 2, 64);
        v += __shfl_xor(v, 4, 64);
        v += __shfl_xor(v, 8, 64);
        if (b == 0) atomicAdd(out, v);
    }
}

// ---------------------------------------------------------------------------
extern "C" void kernel_launch(void* const* d_in, const int* in_sizes, int n_in,
                              void* d_out, int out_size, void* d_ws, size_t ws_size,
                              hipStream_t stream) {
    const float* A      = (const float*)d_in[0]; // inputs [128,512,1024]
    const float* W      = (const float*)d_in[1]; // [50,1024]
    const float* bias   = (const float*)d_in[2]; // [50]
    const float* T      = (const float*)d_in[3]; // [52,52]
    const int*   lens   = (const int*)d_in[4];   // [128]
    const int*   labels = (const int*)d_in[5];   // [128,512]
    float* out = (float*)d_out;
    float* PE  = (float*)d_ws;                   // 65536*50*4 = 13.1 MB

    hipMemsetAsync(d_out, 0, sizeof(float), stream);
    gemm_logits<<<dim3((BB * SS) / 64), dim3(256), 0, stream>>>(A, W, bias, PE);
    crf_fwd<<<dim3(8), dim3(128), 0, stream>>>(PE, T, lens, labels, out);
}

// Round 4
// 536.283 us; speedup vs baseline: 1.0727x; 1.0640x over previous
//
#include <hip/hip_runtime.h>
#include <stdint.h>

#define LBL 50
#define NL 52
#define L2E 1.4426950408889634f
#define BB 128
#define SS 512
#define DD 1024

typedef __attribute__((ext_vector_type(8))) short short8;
typedef __attribute__((ext_vector_type(4))) float float4v;
typedef __attribute__((ext_vector_type(2))) float float2v;

union S8U { unsigned int u[4]; short8 s; };

static __device__ __forceinline__ unsigned int f2bf(float f) {
    union { float f; unsigned int u; } v; v.f = f;
    unsigned int r = v.u + 0x7fffu + ((v.u >> 16) & 1u);
    return r >> 16;
}

// ---------------------------------------------------------------------------
// Kernel 0: W [50,1024] f32 -> Wbf [64,1024] bf16 (rows 50..63 zero), rounded.
// ---------------------------------------------------------------------------
__global__ __launch_bounds__(256) void wconv(
    const float* __restrict__ W, unsigned short* __restrict__ Wbf)
{
    int i = blockIdx.x * 256 + threadIdx.x;   // 0..65535
    int r = i >> 10, c = i & 1023;
    float v = (r < LBL) ? W[r * DD + c] : 0.f;
    Wbf[i] = (unsigned short)f2bf(v);
}

// ---------------------------------------------------------------------------
// Kernel 1: PEp[r, c] = exp(sum_d A[r,d]*W[c,d] + b[c]) for c<50, else 0.
// Padded [r][64] output. LDS-free: A-frags straight from global (trunc-pack
// via v_perm), B-frags from pre-converted Wbf (L2-resident).
// ---------------------------------------------------------------------------
__global__ __launch_bounds__(256) void gemm_pe(
    const float* __restrict__ A,            // [65536,1024]
    const unsigned short* __restrict__ Wbf, // [64,1024] bf16
    const float* __restrict__ bias,         // [50]
    float* __restrict__ PEp)                // [65536,64]
{
    const int tid  = threadIdx.x;
    const int lane = tid & 63;
    const int wv   = tid >> 6;
    const int mrow = lane & 15;
    const int quad = lane >> 4;
    const int row  = blockIdx.x * 64 + wv * 16 + mrow;

    const uint4* arow = (const uint4*)(A + (size_t)row * DD);

    float4v acc[4];
#pragma unroll
    for (int i = 0; i < 4; ++i) acc[i] = (float4v){0.f, 0.f, 0.f, 0.f};

#pragma unroll 4
    for (int kc = 0; kc < DD; kc += 32) {
        uint4 u0 = arow[(kc >> 2) + quad * 2];
        uint4 u1 = arow[(kc >> 2) + quad * 2 + 1];
        S8U a;
        a.u[0] = __builtin_amdgcn_perm(u0.y, u0.x, 0x07060302u);
        a.u[1] = __builtin_amdgcn_perm(u0.w, u0.z, 0x07060302u);
        a.u[2] = __builtin_amdgcn_perm(u1.y, u1.x, 0x07060302u);
        a.u[3] = __builtin_amdgcn_perm(u1.w, u1.z, 0x07060302u);
#pragma unroll
        for (int nt = 0; nt < 4; ++nt) {
            short8 bf = *(const short8*)(Wbf + (size_t)(nt * 16 + mrow) * DD + kc + quad * 8);
            acc[nt] = __builtin_amdgcn_mfma_f32_16x16x32_bf16(a.s, bf, acc[nt], 0, 0, 0);
        }
    }
    // epilogue: C[row=quad*4+r][col=nt*16+mrow]
    const int r0 = blockIdx.x * 64 + wv * 16 + quad * 4;
#pragma unroll
    for (int nt = 0; nt < 4; ++nt) {
        int col = nt * 16 + mrow;
        float bv = (col < LBL) ? bias[col] : 0.f;
#pragma unroll
        for (int rr = 0; rr < 4; ++rr) {
            float val = (col < LBL) ? __builtin_amdgcn_exp2f((acc[nt][rr] + bv) * L2E) : 0.f;
            PEp[(size_t)(r0 + rr) * 64 + col] = val;
        }
    }
}

// ---------------------------------------------------------------------------
// Kernel 2: MFMA-batched CRF forward, 8 blocks x 16 chains.
// Padded PE rows -> 4 aligned dwordx4 per step; depth-4 register ring;
// every-step 1-stale power-of-2 rescale (branch-free).
// ---------------------------------------------------------------------------
__global__ __launch_bounds__(128) void crf_fwd(
    const float* __restrict__ PE,     // [65536,64] padded exp(logits)
    const float* __restrict__ T,      // [52,52]
    const int*   __restrict__ lens,   // [128]
    const int*   __restrict__ labels, // [128,512]
    float* __restrict__ out)          // [1], pre-zeroed
{
    const int g    = blockIdx.x;
    const int tid  = threadIdx.x;
    const int lane = tid & 63;
    const int wv   = tid >> 6;
    const int b    = lane & 15;
    const int q    = lane >> 4;

    __shared__ float gold_sh[16];
    float norm_e = 0.f;

    if (wv == 0) {
        const int bb   = g * 16 + b;
        const int lenl = lens[bb];

        // constant A-frags: ET[i][k] e^T, A[m=lane&15][k=q*8+reg]
        short8 afr[4][2];
#pragma unroll
        for (int it = 0; it < 4; ++it) {
            int i = it * 16 + b;
#pragma unroll
            for (int jt = 0; jt < 2; ++jt) {
                S8U pk;
#pragma unroll
                for (int h = 0; h < 4; ++h) {
                    int k0 = jt * 32 + q * 8 + 2 * h;
                    float v0 = (i < NL && k0     < NL) ? __builtin_amdgcn_exp2f(T[i * NL + k0]     * L2E) : 0.f;
                    float v1 = (i < NL && k0 + 1 < NL) ? __builtin_amdgcn_exp2f(T[i * NL + k0 + 1] * L2E) : 0.f;
                    pk.u[h] = f2bf(v0) | (f2bf(v1) << 16);
                }
                afr[it][jt] = pk.s;
            }
        }

        const int addrLo = (b + 16 * ((q & 1) * 2 + 0)) * 4;
        const int addrHi = (b + 16 * ((q & 1) * 2 + 1)) * 4;
        const int addrB  = b * 4;
        const bool qhi = (q >= 2);

        // per-lane base: 16B-aligned float4 stream, row stride = 16 float4s
        const float4* lb = (const float4*)(PE + (size_t)bb * SS * 64 + q * 4);

#define LOADP4(dst, trow) do {                                           \
        const float4* _p = lb + (size_t)(trow) * 16;                     \
        float4 _a0 = _p[0], _a1 = _p[4], _a2 = _p[8], _a3 = _p[12];      \
        dst[0]=_a0.x;  dst[1]=_a0.y;  dst[2]=_a0.z;  dst[3]=_a0.w;       \
        dst[4]=_a1.x;  dst[5]=_a1.y;  dst[6]=_a1.z;  dst[7]=_a1.w;       \
        dst[8]=_a2.x;  dst[9]=_a2.y;  dst[10]=_a2.z; dst[11]=_a2.w;      \
        dst[12]=_a3.x; dst[13]=_a3.y; dst[14]=_a3.z; dst[15]=_a3.w;      \
    } while (0)

        // init E_1[i][b] = PE[row0][i] * e^{T[i][START]}
        float E[16];
        {
            float p0[16];
            LOADP4(p0, 0);
#pragma unroll
            for (int k = 0; k < 16; ++k) {
                int i = (k >> 2) * 16 + q * 4 + (k & 3);
                float ets = (i < NL) ? __builtin_amdgcn_exp2f(T[i * NL + LBL] * L2E) : 0.f;
                E[k] = p0[k] * ets;
            }
        }

        float r0[16], r1[16], r2[16], r3[16];
        LOADP4(r0, 1); LOADP4(r1, 2); LOADP4(r2, 3); LOADP4(r3, 4);

        float ncap = 1.0f;
        int lcap = 0, lsum = 0, ebp = 127;

#define STEP(PC, t) do {                                                          \
        unsigned int pr[4][2];                                                    \
        _Pragma("unroll")                                                         \
        for (int tile = 0; tile < 4; ++tile) {                                    \
            pr[tile][0] = __builtin_amdgcn_perm(__float_as_uint(E[tile*4+1]),     \
                                                __float_as_uint(E[tile*4+0]), 0x07060302u); \
            pr[tile][1] = __builtin_amdgcn_perm(__float_as_uint(E[tile*4+3]),     \
                                                __float_as_uint(E[tile*4+2]), 0x07060302u); \
        }                                                                         \
        S8U bfr[2];                                                               \
        _Pragma("unroll")                                                         \
        for (int jt = 0; jt < 2; ++jt) {                                          \
            _Pragma("unroll")                                                     \
            for (int u = 0; u < 4; ++u) {                                         \
                int adr = (u < 2) ? addrLo : addrHi;                              \
                int vLo = __builtin_amdgcn_ds_bpermute(adr, (int)pr[jt*2+0][u&1]);\
                int vHi = __builtin_amdgcn_ds_bpermute(adr, (int)pr[jt*2+1][u&1]);\
                bfr[jt].u[u] = (unsigned int)(qhi ? vHi : vLo);                   \
            }                                                                     \
        }                                                                         \
        const float4v zz = (float4v){0.f, 0.f, 0.f, 0.f};                         \
        float4v acc[4];                                                           \
        _Pragma("unroll")                                                         \
        for (int it = 0; it < 4; ++it) {                                          \
            float4v a0 = __builtin_amdgcn_mfma_f32_16x16x32_bf16(afr[it][0], bfr[0].s, zz, 0, 0, 0); \
            acc[it]    = __builtin_amdgcn_mfma_f32_16x16x32_bf16(afr[it][1], bfr[1].s, a0, 0, 0, 0); \
        }                                                                         \
        bool cap = ((t) == lenl);                                                 \
        ncap = cap ? acc[3][3] : ncap;                                            \
        lcap = cap ? lsum : lcap;                                                 \
        float s = __uint_as_float((unsigned int)(254 - ebp) << 23);               \
        lsum += 127 - ebp;                                                        \
        int myeb = (int)((__float_as_uint(acc[0][0]) >> 23) & 0xffu);             \
        ebp = __builtin_amdgcn_ds_bpermute(addrB, myeb);                          \
        float2v s2 = (float2v){s, s};                                             \
        _Pragma("unroll")                                                         \
        for (int h = 0; h < 8; ++h) {                                             \
            float2v d2 = (float2v){acc[h>>1][(h&1)*2], acc[h>>1][(h&1)*2+1]};     \
            float2v p2 = (float2v){PC[2*h], PC[2*h+1]};                           \
            float2v e2 = d2 * p2 * s2;                                            \
            E[2*h] = e2.x; E[2*h+1] = e2.y;                                       \
        }                                                                         \
        int _tn = (t) + 4; _tn = (_tn < SS) ? _tn : (SS - 1);                     \
        LOADP4(PC, _tn);                                                          \
    } while (0)

        for (int t0 = 1; t0 <= SS; t0 += 4) {
            STEP(r0, t0);
            STEP(r1, t0 + 1);
            STEP(r2, t0 + 2);
            STEP(r3, t0 + 3);
        }
#undef STEP
#undef LOADP4

        norm_e = (__builtin_amdgcn_logf(ncap) - (float)lcap) * (1.0f / L2E);
    } else {
        // wave 1: gold scores, 4 lanes per batch
        const int lb2 = lane >> 2;
        const int ph  = lane & 3;
        const int bb  = g * 16 + lb2;
        const int len = lens[bb];
        const size_t base = (size_t)bb * SS;
        float un2 = 0.f, bi = 0.f;
        for (int t = ph; t < len; t += 4) {
            int lab = labels[base + t];
            un2 += __builtin_amdgcn_logf(PE[(base + t) * 64 + lab]); // log2
            int prev = (t == 0) ? LBL : labels[base + t - 1];
            bi += T[lab * NL + prev];
        }
        float gsum = un2 * (1.0f / L2E) + bi;
        gsum += __shfl_xor(gsum, 1, 64);
        gsum += __shfl_xor(gsum, 2, 64);
        if (ph == 0) {
            gsum += T[(NL - 1) * NL + labels[base + len - 1]];
            gold_sh[lb2] = gsum;
        }
    }

    __syncthreads();
    if (wv == 0 && q == 0) { // lanes 0..15
        float v = norm_e - gold_sh[b];
        v += __shfl_xor(v, 1, 64);
        v += __shfl_xor(v, 2, 64);
        v += __shfl_xor(v, 4, 64);
        v += __shfl_xor(v, 8, 64);
        if (b == 0) atomicAdd(out, v);
    }
}

// ---------------------------------------------------------------------------
extern "C" void kernel_launch(void* const* d_in, const int* in_sizes, int n_in,
                              void* d_out, int out_size, void* d_ws, size_t ws_size,
                              hipStream_t stream) {
    const float* A      = (const float*)d_in[0]; // inputs [128,512,1024]
    const float* W      = (const float*)d_in[1]; // [50,1024]
    const float* bias   = (const float*)d_in[2]; // [50]
    const float* T      = (const float*)d_in[3]; // [52,52]
    const int*   lens   = (const int*)d_in[4];   // [128]
    const int*   labels = (const int*)d_in[5];   // [128,512]
    float* out = (float*)d_out;

    float* PEp = (float*)d_ws;                               // 65536*64*4 = 16.78 MB
    unsigned short* Wbf = (unsigned short*)((char*)d_ws + (size_t)65536 * 64 * 4); // 131 KB

    hipMemsetAsync(d_out, 0, sizeof(float), stream);
    wconv<<<dim3(256), dim3(256), 0, stream>>>(W, Wbf);
    gemm_pe<<<dim3((BB * SS) / 64), dim3(256), 0, stream>>>(A, Wbf, bias, PEp);
    crf_fwd<<<dim3(8), dim3(128), 0, stream>>>(PEp, T, lens, labels, out);
}